// Round 17
// baseline (160.336 us; speedup 1.0000x reference)
//
#include <hip/hip_runtime.h>
#include <math.h>

typedef __bf16 bf16;
typedef __bf16 bf16x8 __attribute__((ext_vector_type(8)));
typedef __bf16 bf16x4 __attribute__((ext_vector_type(4)));
typedef float  f32x4  __attribute__((ext_vector_type(4)));

namespace {
constexpr int B_ = 2, S_ = 2048, HID_ = 1024, H_ = 16, D_ = 64, R_ = 128, NREL_ = 257;
constexpr float LOG2E_ = 1.44269504f;
constexpr float QSC_ = 0.125f * LOG2E_;   // 1/sqrt(D) and log2(e), folded into Q
}

static __device__ __forceinline__ f32x4 mfma16(bf16x8 a, bf16x8 b, f32x4 c) {
  return __builtin_amdgcn_mfma_f32_16x16x32_bf16(a, b, c, 0, 0, 0);
}
static __device__ __forceinline__ void split2(float f, bf16 &hi, bf16 &lo) {
  hi = (bf16)f; lo = (bf16)(f - (float)hi);
}
static __device__ __forceinline__ float fexp2(float x) {
  return __builtin_amdgcn_exp2f(x);
}
// async global->LDS, 16B per lane. dst must be wave-uniform base (+lane*16 by HW).
static __device__ __forceinline__ void gload16(const bf16* g, bf16* l) {
  __builtin_amdgcn_global_load_lds(
      (const __attribute__((address_space(1))) void*)g,
      (__attribute__((address_space(3))) void*)l, 16, 0, 0);
}

// ---------------- prep: mask, rkE*8, rvE^T, hidden split (Ah/Al), W -> bf16
__global__ __launch_bounds__(256) void prep_kernel(
    const float* __restrict__ st_mask, const float* __restrict__ rkE,
    const float* __restrict__ rvE, const float* __restrict__ hidden,
    const float* __restrict__ Wq, const float* __restrict__ Wk,
    const float* __restrict__ Wv,
    float* __restrict__ msk2, bf16* __restrict__ rkEb, bf16* __restrict__ rvTb,
    bf16* __restrict__ Ahg, bf16* __restrict__ Alg, bf16* __restrict__ Wbg)
{
  const int t0 = blockIdx.x * 256 + threadIdx.x;
  const int NT = gridDim.x * 256;
  for (int t = t0; t < B_ * S_; t += NT)
    msk2[t] = (1.f - st_mask[t]) * -10000.f * LOG2E_;
  for (int t = t0; t < 272 * 64; t += NT) {
    const int bk = t >> 6, d = t & 63;
    rkEb[t] = (bk < NREL_) ? (bf16)(rkE[bk * D_ + d] * 8.0f) : (bf16)0.f;
  }
  for (int t = t0; t < 64 * 288; t += NT) {
    const int d = t / 288, c = t - d * 288;
    rvTb[t] = (c < NREL_) ? (bf16)rvE[c * D_ + d] : (bf16)0.f;
  }
  for (int t = t0; t < (B_ * S_ * HID_) / 4; t += NT) {
    const float4 a = ((const float4*)hidden)[t];
    const float av[4] = {a.x, a.y, a.z, a.w};
    bf16x4 h, o;
#pragma unroll
    for (int i = 0; i < 4; ++i) {
      bf16 th, tl;
      split2(av[i], th, tl);
      h[i] = th; o[i] = tl;
    }
    *(bf16x4*)&Ahg[t * 4] = h;
    *(bf16x4*)&Alg[t * 4] = o;
  }
  for (int t = t0; t < 3 * (HID_ * HID_) / 4; t += NT) {
    const int s = t >> 18, i = t & 262143;
    const float4 wv4 = ((const float4*)(s == 0 ? Wq : s == 1 ? Wk : Wv))[i];
    bf16x4 h;
    h[0] = (bf16)wv4.x; h[1] = (bf16)wv4.y; h[2] = (bf16)wv4.z; h[3] = (bf16)wv4.w;
    *(bf16x4*)&Wbg[s * 1048576 + i * 4] = h;
  }
}

// ---------------- qkv GEMM (passed r10-r16). V written TILED [B,H, S/64, D, 64]
// with sigma-permuted columns (PV A-operand needs no shuffle).
__global__ __launch_bounds__(256, 2) void qkv_mfma_kernel(
    const bf16* __restrict__ Ahg, const bf16* __restrict__ Alg,
    const bf16* __restrict__ Wbg,
    const float* __restrict__ bq, const float* __restrict__ bk,
    const float* __restrict__ bv,
    bf16* __restrict__ Qh, bf16* __restrict__ Ql,
    bf16* __restrict__ Kb, bf16* __restrict__ Vt)
{
  const int swz = ((int)blockIdx.x & 7) * 64 + ((int)blockIdx.x >> 3);
  const int m0 = (swz >> 4) * 128;
  const int n0 = (swz & 15) * 64;
  const int tid = threadIdx.x;
  const int l = tid & 63, w = tid >> 6;
  const int cl = l & 15, g = l >> 4;

  __shared__ __align__(16) bf16 AhS[2][4096];
  __shared__ __align__(16) bf16 AlS[2][4096];
  __shared__ __align__(16) bf16 WS[2][3][2048];

  const int r0 = tid >> 2;
  const int csw = (((tid & 3) ^ (r0 & 3)) << 3);
  const size_t aoff0 = (size_t)(m0 + r0) * HID_ + csw;
  const size_t aoff1 = (size_t)(m0 + 64 + r0) * HID_ + csw;
  const size_t woff  = (size_t)(n0 + r0) * HID_ + csw;
  const int wb = w * 512;

  const int rA0 = w * 16 + cl;
  const int eA0 = rA0 * 32 + 8 * (g ^ (rA0 & 3));
  const int eA1 = eA0 + 2048;
  const int eW  = cl * 32 + 8 * (g ^ (cl & 3));

  f32x4 acc[2][3][4];
#pragma unroll
  for (int hf = 0; hf < 2; ++hf)
#pragma unroll
    for (int s = 0; s < 3; ++s)
#pragma unroll
      for (int nf = 0; nf < 4; ++nf)
#pragma unroll
        for (int i = 0; i < 4; ++i) acc[hf][s][nf][i] = 0.f;

  gload16(Ahg + aoff0, &AhS[0][wb]);
  gload16(Ahg + aoff1, &AhS[0][2048 + wb]);
  gload16(Alg + aoff0, &AlS[0][wb]);
  gload16(Alg + aoff1, &AlS[0][2048 + wb]);
  gload16(Wbg + woff,           &WS[0][0][wb]);
  gload16(Wbg + 1048576 + woff, &WS[0][1][wb]);
  gload16(Wbg + 2097152 + woff, &WS[0][2][wb]);
  __syncthreads();

  int cur = 0;
  for (int kt = 0; kt < HID_ / 32; ++kt) {
    if (kt + 1 < HID_ / 32) {
      const size_t ko = (size_t)(kt + 1) * 32;
      bf16* ah = &AhS[cur ^ 1][0]; bf16* al = &AlS[cur ^ 1][0];
      gload16(Ahg + aoff0 + ko, ah + wb);
      gload16(Ahg + aoff1 + ko, ah + 2048 + wb);
      gload16(Alg + aoff0 + ko, al + wb);
      gload16(Alg + aoff1 + ko, al + 2048 + wb);
      gload16(Wbg + woff + ko,           &WS[cur ^ 1][0][wb]);
      gload16(Wbg + 1048576 + woff + ko, &WS[cur ^ 1][1][wb]);
      gload16(Wbg + 2097152 + woff + ko, &WS[cur ^ 1][2][wb]);
    }

    const bf16x8 fah0 = *(const bf16x8*)&AhS[cur][eA0];
    const bf16x8 fah1 = *(const bf16x8*)&AhS[cur][eA1];
    const bf16x8 fal0 = *(const bf16x8*)&AlS[cur][eA0];
    const bf16x8 fal1 = *(const bf16x8*)&AlS[cur][eA1];
#pragma unroll
    for (int s = 0; s < 3; ++s)
#pragma unroll
      for (int nf = 0; nf < 4; ++nf) {
        const bf16x8 fb = *(const bf16x8*)&WS[cur][s][nf * 512 + eW];
        acc[0][s][nf] = mfma16(fah0, fb, acc[0][s][nf]);
        acc[0][s][nf] = mfma16(fal0, fb, acc[0][s][nf]);
        acc[1][s][nf] = mfma16(fah1, fb, acc[1][s][nf]);
        acc[1][s][nf] = mfma16(fal1, fb, acc[1][s][nf]);
      }
    __syncthreads();
    cur ^= 1;
  }

  const float* bs_[3] = {bq, bk, bv};
#pragma unroll
  for (int s = 0; s < 3; ++s)
#pragma unroll
    for (int nf = 0; nf < 4; ++nf) {
      const int n = n0 + nf * 16 + cl;
      const float bias = bs_[s][n];
      const int hd = n >> 6, d = n & 63;
#pragma unroll
      for (int hf = 0; hf < 2; ++hf)
#pragma unroll
        for (int reg = 0; reg < 4; ++reg) {
          const int m = m0 + hf * 64 + w * 16 + g * 4 + reg;
          const int b = m >> 11, sq = m & (S_ - 1);
          const float val = acc[hf][s][nf][reg] + bias;
          if (s == 0) {
            bf16 h, o; split2(val * QSC_, h, o);
            const size_t idx = ((size_t)(b * H_ + hd) * S_ + sq) * D_ + d;
            Qh[idx] = h; Ql[idx] = o;
          } else if (s == 1) {
            Kb[((size_t)(b * H_ + hd) * S_ + sq) * D_ + d] = (bf16)val;
          } else {
            const int jo = sq & 63;
            const int mc = (jo & 32) | (((jo >> 3) & 1) << 4) | (((jo >> 2) & 1) << 3)
                         | (((jo >> 4) & 1) << 2) | (jo & 3);
            Vt[(((size_t)(b * H_ + hd) * (S_ / 64) + (sq >> 6)) * D_ + d) * 64 + mc]
                = (bf16)val;
          }
        }
    }
}

// ---------------- attention v17: r16 + row-sums via ones-MFMA (3 mode-selected
// accumulators replace all lsum/plo/phi VALU adds on far tiles). T stride 264.
__global__ __launch_bounds__(512, 4) void attn_kernel(
    const bf16* __restrict__ Qh, const bf16* __restrict__ Ql,
    const bf16* __restrict__ Kb, const bf16* __restrict__ Vt,
    const float* __restrict__ msk2, const bf16* __restrict__ rkEb,
    const bf16* __restrict__ rvTb, float* __restrict__ out)
{
  constexpr int NT = S_ / 64;    // 32 tiles
  const int swz = ((int)blockIdx.x & 7) * 128 + ((int)blockIdx.x >> 3);
  const int qt = swz & 31, h = (swz >> 5) & 15, b = swz >> 9;
  const int q0 = qt * 64;
  const int tid = threadIdx.x;
  const int l = tid & 63, w = tid >> 6;
  const int wq = (w & 3) * 16;
  const int wh = w >> 2;
  const int cl = l & 15, g = l >> 4, kg8 = g * 8;
  const int lq = wq + cl;

  // K triple (24K) + V double (16K); ctxred [2][64][36] f32 aliases after loop
  __shared__ __align__(16) unsigned char U[40960];
  __shared__ __align__(16) bf16 T[64][264];     // rs then relp; col 256 = rs_hi
  __shared__ __align__(16) bf16 msk_l[S_];      // bf16 mask*log2e
  __shared__ float red3[2][3][64];              // MFMA sums: plo/phi/mid per q
  __shared__ float redm[2][2][64];              // mixed-tile scalar plo/phi

  bf16* kA = (bf16*)&U[0];
  bf16* kB = (bf16*)&U[8192];
  bf16* kC = (bf16*)&U[16384];
  bf16* vA = (bf16*)&U[24576];
  bf16* vB = (bf16*)&U[32768];
  float* ctxredf = (float*)&U[0];               // after loop

  const size_t bh = (size_t)(b * H_ + h) * S_;
  const bf16* Kbase = Kb + bh * D_;
  const bf16* Vbase = Vt + bh * D_;
  const float* mbase = msk2 + b * S_;

  const int tKr = tid >> 3;
  const int koff = tKr * 64 + (((tid & 7) ^ (tKr & 7)) << 3);

  gload16(Kbase + koff,        kA + w * 512);
  gload16(Kbase + 4096 + koff, kB + w * 512);
  gload16(Vbase + koff,        vA + w * 512);

  {
    const float4 m4 = *(const float4*)(mbase + tid * 4);
    bf16x4 mb;
    mb[0] = (bf16)m4.x; mb[1] = (bf16)m4.y; mb[2] = (bf16)m4.z; mb[3] = (bf16)m4.w;
    *(bf16x4*)&msk_l[tid * 4] = mb;
  }

  bf16x8 qh0, qh1, ql0, ql1;
  {
    const size_t base = (bh + q0 + lq) * D_ + kg8;
    qh0 = *(const bf16x8*)(Qh + base);
    qh1 = *(const bf16x8*)(Qh + base + 32);
    ql0 = *(const bf16x8*)(Ql + base);
    ql1 = *(const bf16x8*)(Ql + base + 32);
  }

  // rel key scores into T (stride 264; nt==16 writes only col 256, lane g==0)
  {
    const int nt0 = wh ? 9 : 0, ntE = wh ? 17 : 9;
    for (int nt = nt0; nt < ntE; ++nt) {
      f32x4 r; r[0] = r[1] = r[2] = r[3] = 0.f;
      const bf16x8 a0 = *(const bf16x8*)(rkEb + (size_t)(nt * 16 + cl) * 64 + kg8);
      const bf16x8 a1 = *(const bf16x8*)(rkEb + (size_t)(nt * 16 + cl) * 64 + 32 + kg8);
      r = mfma16(a0, qh0, r); r = mfma16(a0, ql0, r);
      r = mfma16(a1, qh1, r); r = mfma16(a1, ql1, r);
      if (nt < 16) {
        bf16x4 pk;
#pragma unroll
        for (int reg = 0; reg < 4; ++reg) pk[reg] = (bf16)r[reg];
        *(bf16x4*)&T[lq][nt * 16 + g * 4] = pk;
      } else if (g == 0) {
        T[lq][256] = (bf16)r[0];
      }
    }
  }
  __syncthreads();

  const float rs_lo = (float)T[lq][0];
  const float rs_hi = (float)T[lq][256];
  const int qg = q0 + lq;

  f32x4 ctx[4];
#pragma unroll
  for (int nf = 0; nf < 4; ++nf) { ctx[nf][0]=0.f; ctx[nf][1]=0.f; ctx[nf][2]=0.f; ctx[nf][3]=0.f; }
  f32x4 sumLo, sumHi, sumMid;
  sumLo[0]=sumLo[1]=sumLo[2]=sumLo[3]=0.f;
  sumHi[0]=sumHi[1]=sumHi[2]=sumHi[3]=0.f;
  sumMid[0]=sumMid[1]=sumMid[2]=sumMid[3]=0.f;
  float plo = 0.f, phi = 0.f;   // mixed-tile scalar parts only
  bf16x8 ones8;
#pragma unroll
  for (int i = 0; i < 8; ++i) ones8[i] = (bf16)1.0f;

  const int r00 = wh * 32 + cl, r10 = wh * 32 + 16 + cl;
  const int e00 = r00 * 64 + 8 * (g ^ (r00 & 7)), e01 = r00 * 64 + 8 * ((4 + g) ^ (r00 & 7));
  const int e10 = r10 * 64 + 8 * (g ^ (r10 & 7)), e11 = r10 * 64 + 8 * ((4 + g) ^ (r10 & 7));
  int fv0, fv1, fv2, fv3;
  {
    const int rd0 = cl, rd1 = 16 + cl, rd2 = 32 + cl, rd3 = 48 + cl;
    fv0 = rd0 * 64 + 8 * ((4 * wh + g) ^ (rd0 & 7));
    fv1 = rd1 * 64 + 8 * ((4 * wh + g) ^ (rd1 & 7));
    fv2 = rd2 * 64 + 8 * ((4 * wh + g) ^ (rd2 & 7));
    fv3 = rd3 * 64 + 8 * ((4 * wh + g) ^ (rd3 & 7));
  }

  bf16* kR = kA; bf16* kM = kB; bf16* kW = kC;
  bf16* vR = vA; bf16* vW = vB;

  for (int kt = 0; kt < NT; ++kt) {
    if (kt + 2 < NT) gload16(Kbase + (size_t)(kt + 2) * 4096 + koff, kW + w * 512);
    if (kt + 1 < NT) gload16(Vbase + (size_t)(kt + 1) * 4096 + koff, vW + w * 512);

    const bf16x8 a00 = *(const bf16x8*)&kR[e00];
    const bf16x8 a01 = *(const bf16x8*)&kR[e01];
    const bf16x8 a10 = *(const bf16x8*)&kR[e10];
    const bf16x8 a11 = *(const bf16x8*)&kR[e11];

    f32x4 s0, s1;
    s0[0]=s0[1]=s0[2]=s0[3]=0.f; s1[0]=s1[1]=s1[2]=s1[3]=0.f;
    __builtin_amdgcn_s_setprio(1);
    s0 = mfma16(a00, qh0, s0); s0 = mfma16(a00, ql0, s0);
    s0 = mfma16(a01, qh1, s0); s0 = mfma16(a01, ql1, s0);
    s1 = mfma16(a10, qh0, s1); s1 = mfma16(a10, ql0, s1);
    s1 = mfma16(a11, qh1, s1); s1 = mfma16(a11, ql1, s1);
    __builtin_amdgcn_s_setprio(0);

    const int j0 = kt * 64 + wh * 32;
    const bf16x4 mb0 = *(const bf16x4*)&msk_l[j0 + g * 4];
    const bf16x4 mb1 = *(const bf16x4*)&msk_l[j0 + 16 + g * 4];
    const int dlt = kt * 64 - q0;
    const int mode = (dlt <= -192) ? 0 : (dlt >= 192 ? 1 : 2);

    bf16x4 pk0, pk1;
#pragma unroll
    for (int nf = 0; nf < 2; ++nf) {
      const f32x4 sa = nf ? s1 : s0;
      const bf16x4 mkv = nf ? mb1 : mb0;
      float mks[4];
#pragma unroll
      for (int i = 0; i < 4; ++i) mks[i] = (float)mkv[i];
      float p[4];
      if (mode == 0) {
#pragma unroll
        for (int reg = 0; reg < 4; ++reg) p[reg] = fexp2(sa[reg] + rs_lo + mks[reg]);
      } else if (mode == 1) {
#pragma unroll
        for (int reg = 0; reg < 4; ++reg) p[reg] = fexp2(sa[reg] + rs_hi + mks[reg]);
      } else {
        const int jb = j0 + nf * 16 + g * 4;
#pragma unroll
        for (int reg = 0; reg < 4; ++reg) {
          const int bkv = jb + reg - qg + R_;
          const int bkc = bkv < 0 ? 0 : (bkv > 2 * R_ ? 2 * R_ : bkv);
          const float pv = fexp2(sa[reg] + (float)T[lq][bkc] + mks[reg]);
          p[reg] = pv;
          if (bkv <= 0)           plo += pv;
          else if (bkv >= 2 * R_) phi += pv;
          else                    T[lq][bkv] = (bf16)pv;   // unique owner cell
        }
      }
      bf16x4 pk;
#pragma unroll
      for (int reg = 0; reg < 4; ++reg) pk[reg] = (bf16)p[reg];
      if (nf == 0) pk0 = pk; else pk1 = pk;
    }

    if (kt < NT - 2)      asm volatile("s_waitcnt vmcnt(2)" ::: "memory");
    else if (kt == NT - 2) asm volatile("s_waitcnt vmcnt(1)" ::: "memory");
    else                  asm volatile("s_waitcnt vmcnt(0)" ::: "memory");
    __builtin_amdgcn_sched_barrier(0);

    const bf16x8 pa = __builtin_shufflevector(pk0, pk1, 0, 1, 2, 3, 4, 5, 6, 7);
    __builtin_amdgcn_s_setprio(1);
    ctx[0] = mfma16(pa, *(const bf16x8*)&vR[fv0], ctx[0]);
    ctx[1] = mfma16(pa, *(const bf16x8*)&vR[fv1], ctx[1]);
    ctx[2] = mfma16(pa, *(const bf16x8*)&vR[fv2], ctx[2]);
    ctx[3] = mfma16(pa, *(const bf16x8*)&vR[fv3], ctx[3]);
    // row-sums via ones-MFMA, mode-selected accumulator
    if (mode == 0)      sumLo  = mfma16(pa, ones8, sumLo);
    else if (mode == 1) sumHi  = mfma16(pa, ones8, sumHi);
    else                sumMid = mfma16(pa, ones8, sumMid);
    __builtin_amdgcn_s_setprio(0);

    if (kt < NT - 2) asm volatile("s_waitcnt vmcnt(1)" ::: "memory");
    else             asm volatile("s_waitcnt vmcnt(0)" ::: "memory");
    __builtin_amdgcn_sched_barrier(0);
    __builtin_amdgcn_s_barrier();
    __builtin_amdgcn_sched_barrier(0);

    bf16* t0 = kR; kR = kM; kM = kW; kW = t0;
    bf16* t1 = vR; vR = vW; vW = t1;
  }

  // mixed-tile scalar plo/phi: reduce over the 4 g-groups (q = wq+cl per lane)
  plo += __shfl_xor(plo, 16); plo += __shfl_xor(plo, 32);
  phi += __shfl_xor(phi, 16); phi += __shfl_xor(phi, 32);
  if (l < 16) {
    redm[wh][0][wq + l] = plo;
    redm[wh][1][wq + l] = phi;
  }
  // MFMA sums: all cl lanes duplicate; cl==0 lanes write (q = wq + g*4 + reg)
  if (cl == 0) {
#pragma unroll
    for (int reg = 0; reg < 4; ++reg) {
      const int qr = wq + g * 4 + reg;
      red3[wh][0][qr] = sumLo[reg];
      red3[wh][1][qr] = sumHi[reg];
      red3[wh][2][qr] = sumMid[reg];
    }
  }
  __syncthreads();   // reds ready; all loop LDS reads done (U reusable)

  // exchange non-kept ctx halves via U
  {
    const int nfs = wh ? 0 : 2;
#pragma unroll
    for (int k2 = 0; k2 < 2; ++k2)
#pragma unroll
      for (int reg = 0; reg < 4; ++reg)
        ctxredf[((wh * 64) + wq + g * 4 + reg) * 36 + k2 * 16 + cl] = ctx[nfs + k2][reg];
  }
  if (tid < 64) {
    const float sLo = red3[0][0][tid] + red3[1][0][tid];
    const float sHi = red3[0][1][tid] + red3[1][1][tid];
    const float sMd = red3[0][2][tid] + red3[1][2][tid];
    const float mpl = redm[0][0][tid] + redm[1][0][tid];
    const float mph = redm[0][1][tid] + redm[1][1][tid];
    red3[0][0][tid] = sLo + sHi + sMd;        // lsum
    T[tid][0]       = (bf16)(sLo + mpl);      // plo -> bucket 0
    red3[0][2][tid] = sHi + mph;              // phi (scalar tail)
  }
  // zero interior cells whose j is out of range (edge q-tiles only)
  if (q0 < R_ || q0 > S_ - R_ - 64) {
    for (int t = tid; t < 64 * 256; t += 512) {
      const int r = t >> 8, c = t & 255;
      if (c >= 1) {
        const int j = q0 + r + c - R_;
        if (j < 0 || j >= S_) T[r][c] = (bf16)0.f;
      }
    }
  }
  __syncthreads();

  // complete kept halves with peer's partials
  const int nfa = wh ? 2 : 0;
  f32x4 cx0 = ctx[nfa], cx1 = ctx[nfa + 1];
#pragma unroll
  for (int reg = 0; reg < 4; ++reg) {
    cx0[reg] += ctxredf[(((wh ^ 1) * 64) + wq + g * 4 + reg) * 36 + cl];
    cx1[reg] += ctxredf[(((wh ^ 1) * 64) + wq + g * 4 + reg) * 36 + 16 + cl];
  }

  // rel-value GEMM: buckets 0..255 (bucket 256 via scalar phi-tail)
#pragma unroll
  for (int ks = 0; ks < 8; ++ks) {
    const bf16x8 pa = *(const bf16x8*)&T[lq][ks * 32 + kg8];
    const bf16x8 v0 = *(const bf16x8*)(rvTb + (size_t)(wh * 32 + cl) * 288 + ks * 32 + kg8);
    const bf16x8 v1 = *(const bf16x8*)(rvTb + (size_t)(wh * 32 + 16 + cl) * 288 + ks * 32 + kg8);
    __builtin_amdgcn_s_setprio(1);
    cx0 = mfma16(pa, v0, cx0);
    cx1 = mfma16(pa, v1, cx1);
    __builtin_amdgcn_s_setprio(0);
  }
  const float rv256a = (float)rvTb[(size_t)(wh * 32 + cl) * 288 + 256];
  const float rv256b = (float)rvTb[(size_t)(wh * 32 + 16 + cl) * 288 + 256];

#pragma unroll
  for (int reg = 0; reg < 4; ++reg) {
    const int qrow = wq + g * 4 + reg;
    const float invl = 1.f / red3[0][0][qrow];
    const float phq  = red3[0][2][qrow];
    float* op = out + (size_t)(b * S_ + q0 + qrow) * HID_ + h * 64 + wh * 32;
    op[cl]      = (cx0[reg] + phq * rv256a) * invl;
    op[16 + cl] = (cx1[reg] + phq * rv256b) * invl;
  }
}

extern "C" void kernel_launch(void* const* d_in, const int* in_sizes, int n_in,
                              void* d_out, int out_size, void* d_ws, size_t ws_size,
                              hipStream_t stream)
{
  (void)in_sizes; (void)n_in; (void)out_size; (void)ws_size;
  const float* hidden  = (const float*)d_in[0];
  const float* st_mask = (const float*)d_in[1];
  const float* Wq = (const float*)d_in[2];
  const float* bq = (const float*)d_in[3];
  const float* Wk = (const float*)d_in[4];
  const float* bk = (const float*)d_in[5];
  const float* Wv = (const float*)d_in[6];
  const float* bv = (const float*)d_in[7];
  const float* rkE = (const float*)d_in[8];
  const float* rvE = (const float*)d_in[9];
  float* out = (float*)d_out;

  const size_t per = (size_t)B_ * H_ * S_ * D_;   // 4,194,304 elements
  char* wsb = (char*)d_ws;
  float* msk2 = (float*)wsb;                               // 16384 B
  bf16*  rkEb = (bf16*)(wsb + 16384);                      // 34816 B
  bf16*  rvTb = (bf16*)(wsb + 16384 + 34816);              // 36864 B
  char*  base1 = wsb + 16384 + 34816 + 36864;
  bf16* Qh = (bf16*)base1;
  bf16* Ql = Qh + per;
  bf16* Kb = Ql + per;
  bf16* Vt = Kb + per;
  bf16* Ahg = Vt + per;
  bf16* Alg = Ahg + per;
  bf16* Wbg = Alg + per;

  prep_kernel<<<dim3(1024), 256, 0, stream>>>(
      st_mask, rkE, rvE, hidden, Wq, Wk, Wv, msk2, rkEb, rvTb, Ahg, Alg, Wbg);
  qkv_mfma_kernel<<<dim3(512), 256, 0, stream>>>(
      Ahg, Alg, Wbg, bq, bk, bv, Qh, Ql, Kb, Vt);
  attn_kernel<<<dim3(1024), 512, 0, stream>>>(
      Qh, Ql, Kb, Vt, msk2, rkEb, rvTb, out);
}